// Round 9
// baseline (210.338 us; speedup 1.0000x reference)
//
#include <hip/hip_runtime.h>
#include <stdint.h>

#define SEQ 2048
#define NTOK 4096          // B*S
#define DM 1024

typedef __bf16 bf16x8 __attribute__((ext_vector_type(8)));
typedef __bf16 bf16x4 __attribute__((ext_vector_type(4)));
typedef float f32x4 __attribute__((ext_vector_type(4)));

__device__ __forceinline__ unsigned short f2bf(float f) {
  union { float f; unsigned u; } v; v.f = f;
  return (unsigned short)((v.u + 0x7fffu + ((v.u >> 16) & 1u)) >> 16);
}
__device__ __forceinline__ float bf2f(unsigned short s) {
  union { unsigned u; float f; } v; v.u = ((unsigned)s) << 16; return v.f;
}
// pack two floats to packed bf16 (round-half-up) in ONE v_perm + 2 adds
__device__ __forceinline__ unsigned pkbf(float a, float b) {
  union { float f; unsigned u; } x, y; x.f = a; y.f = b;
  return __builtin_amdgcn_perm(y.u + 0x8000u, x.u + 0x8000u, 0x07060302u);
}

// async global->LDS, 16B per lane. LDS dest must be wave-uniform base + lane*16.
__device__ __forceinline__ void async16(const unsigned short* g, unsigned short* l) {
  __builtin_amdgcn_global_load_lds(
      (const __attribute__((address_space(1))) void*)g,
      (__attribute__((address_space(3))) void*)l, 16, 0, 0);
}

// one kernel casts x + all 4 weights (contiguous in ws)
__global__ __launch_bounds__(256) void cast_all(
    const float* __restrict__ x, const float* __restrict__ wq,
    const float* __restrict__ wk, const float* __restrict__ wv,
    const float* __restrict__ wo, unsigned short* __restrict__ dst) {
  size_t i = ((size_t)blockIdx.x * 256 + threadIdx.x) * 4;
  const float* src; size_t off;
  if (i < (size_t)NTOK * DM) { src = x; off = i; }
  else {
    size_t j = i - (size_t)NTOK * DM;
    int s = (int)(j >> 20);
    src = (s == 0) ? wq : (s == 1) ? wk : (s == 2) ? wv : wo;
    off = j & 1048575u;
  }
  float4 f = *(const float4*)(src + off);
  ushort4 o;
  o.x = f2bf(f.x); o.y = f2bf(f.y); o.z = f2bf(f.z); o.w = f2bf(f.w);
  *(ushort4*)(dst + i) = o;
}

// QKV projection, single-barrier double-buffered K-loop (BK=32).
// 1-D grid, XCD-grouped: each XCD owns a 512-token slab of x for ALL kinds
// (kind 0=Q scaled log2e/8, 1=K, 2=V^T with A/B swapped for coalesced store).
// LDS 16B chunk c of row r stored at c^(r&3) (source-side swizzle).
__global__ __launch_bounds__(256) void qkv_gemm(
    const unsigned short* __restrict__ xb,
    const unsigned short* __restrict__ wqb, const unsigned short* __restrict__ wkb,
    const unsigned short* __restrict__ wvb,
    const float* __restrict__ bq, const float* __restrict__ bk, const float* __restrict__ bv,
    unsigned short* __restrict__ Q, unsigned short* __restrict__ Kd,
    unsigned short* __restrict__ Vt) {
  __shared__ unsigned short As[2][128 * 32], Bs[2][128 * 32];   // 32 KB
  const int gx = blockIdx.x;
  const int kind = gx >> 8;
  const int rr = gx & 255;
  const int tok = 4 * (rr & 7) + ((rr >> 3) & 3);   // 0..31, XCD-grouped
  const int oth = rr >> 5;                           // 0..7
  const unsigned short* A; const unsigned short* Bw;
  int m0, n0;
  if (kind == 2) { A = wvb; Bw = xb; m0 = oth * 128; n0 = tok * 128; }
  else { A = xb; Bw = kind ? wkb : wqb; m0 = tok * 128; n0 = oth * 128; }

  const int tid = threadIdx.x, lane = tid & 63, w = tid >> 6;
  const int wm = (w >> 1) * 64, wn = (w & 1) * 64;
  const int quad = lane >> 4, l16 = lane & 15;
  const int srow = tid >> 2;                        // 0..63
  const int sc = (((tid & 3) ^ (srow & 3)) << 3);   // swizzled source chunk

  f32x4 acc[4][4];
#pragma unroll
  for (int i = 0; i < 4; ++i)
#pragma unroll
    for (int j = 0; j < 4; ++j) { f32x4 z = {0.f, 0.f, 0.f, 0.f}; acc[i][j] = z; }

  // prologue: stage kt=0 into buffer 0
  async16(A + (size_t)(m0 + srow) * 1024 + sc, As[0] + tid * 8);
  async16(A + (size_t)(m0 + 64 + srow) * 1024 + sc, As[0] + 2048 + tid * 8);
  async16(Bw + (size_t)(n0 + srow) * 1024 + sc, Bs[0] + tid * 8);
  async16(Bw + (size_t)(n0 + 64 + srow) * 1024 + sc, Bs[0] + 2048 + tid * 8);

  for (int it = 0; it < 32; ++it) {
    const int cur = it & 1;
    __syncthreads();   // drains prefetch issued a full compute-phase ago
    if (it + 1 < 32) {
      const int kt = (it + 1) * 32, nb = (it + 1) & 1;
      async16(A + (size_t)(m0 + srow) * 1024 + kt + sc, As[nb] + tid * 8);
      async16(A + (size_t)(m0 + 64 + srow) * 1024 + kt + sc, As[nb] + 2048 + tid * 8);
      async16(Bw + (size_t)(n0 + srow) * 1024 + kt + sc, Bs[nb] + tid * 8);
      async16(Bw + (size_t)(n0 + 64 + srow) * 1024 + kt + sc, Bs[nb] + 2048 + tid * 8);
    }
    bf16x8 af[4], bf[4];
#pragma unroll
    for (int i = 0; i < 4; ++i) {
      const int r = wm + i * 16 + l16;
      af[i] = *(const bf16x8*)(As[cur] + r * 32 + ((quad ^ (r & 3)) << 3));
    }
#pragma unroll
    for (int j = 0; j < 4; ++j) {
      const int r = wn + j * 16 + l16;
      bf[j] = *(const bf16x8*)(Bs[cur] + r * 32 + ((quad ^ (r & 3)) << 3));
    }
#pragma unroll
    for (int i = 0; i < 4; ++i)
#pragma unroll
      for (int j = 0; j < 4; ++j)
        acc[i][j] = __builtin_amdgcn_mfma_f32_16x16x32_bf16(af[i], bf[j], acc[i][j], 0, 0, 0);
  }

  if (kind == 2) {
    // m = channel, n = token
#pragma unroll
    for (int i = 0; i < 4; ++i)
#pragma unroll
      for (int j = 0; j < 4; ++j) {
        const int n = n0 + wn + j * 16 + l16;
        const int tb = n >> 11, s = n & 2047;
#pragma unroll
        for (int r = 0; r < 4; ++r) {
          const int m = m0 + wm + i * 16 + quad * 4 + r;
          const int h = m >> 6, d = m & 63;
          Vt[((size_t)(tb * 16 + h) * 64 + d) * SEQ + s] = f2bf(acc[i][j][r] + bv[m]);
        }
      }
  } else {
    const float* bias = (kind == 0) ? bq : bk;
    const float scale = (kind == 0) ? 0.180336880f : 1.0f;  // log2(e)/8 for Q
#pragma unroll
    for (int i = 0; i < 4; ++i)
#pragma unroll
      for (int j = 0; j < 4; ++j) {
        const int col = n0 + wn + j * 16 + l16;
        const float bb = bias[col];
        const int h = col >> 6, d = col & 63;
#pragma unroll
        for (int r = 0; r < 4; ++r) {
          const int m = m0 + wm + i * 16 + quad * 4 + r;
          const int b = m >> 11, s = m & 2047;
          const int bh = b * 16 + h;
          const unsigned short val = f2bf((acc[i][j][r] + bb) * scale);
          if (kind == 0) Q[((size_t)bh * SEQ + s) * 64 + d] = val;
          else           Kd[((size_t)bh * SEQ + s) * 64 + d] = val;
        }
      }
  }
}

// Flash attention, split-K (2 key slices of 1024), S^T form, log2-domain,
// FIXED-MAX softmax P = exp2(s-12) (the -12 rides in the MFMA C-init).
// q-tile 256/block, 4 qq groups/wave; Q staged via all 4 KV buffers then
// consumed to registers; K/V double-buffer, 1 barrier/iter. XCD-aware grid.
__global__ __launch_bounds__(256, 2) void attn_kernel(
    const unsigned short* __restrict__ Q, const unsigned short* __restrict__ Kd,
    const unsigned short* __restrict__ Vt,
    unsigned short* __restrict__ Op, float* __restrict__ Lp) {
  __shared__ unsigned short KV[4][4096];   // 32KB total
  const int gx = blockIdx.x;
  const int xcd = gx & 7;
  const int idx = gx >> 3;                 // 0..63
  const int bh  = xcd * 4 + (idx & 3);
  const int ksl = (idx >> 2) & 1;
  const int q0  = (idx >> 3) * 256;        // 0..7 -> q-tile base
  const int ks0 = ksl << 10;               // key slice base
  const int tid = threadIdx.x, lane = tid & 63, w = tid >> 6;
  const int quad = lane >> 4, l16 = lane & 15;
  const unsigned short* Qp = Q + (size_t)bh * SEQ * 64;
  const unsigned short* Kp = Kd + (size_t)bh * SEQ * 64;
  const unsigned short* Vp = Vt + (size_t)bh * 64 * SEQ;
  const int srow = tid >> 3;
  const int sc = ((tid & 7) ^ (srow & 7)) << 3;   // XOR-swizzled chunk

  // stage Q rows q0..q0+255 into KV[0..3] (64 rows per buffer)
#pragma unroll
  for (int c = 0; c < 8; ++c)
    async16(Qp + (size_t)(q0 + c * 32 + srow) * 64 + sc,
            KV[c >> 1] + (c & 1) * 2048 + tid * 8);
  __syncthreads();

  const int sel = l16 & 7;
  const unsigned short* Qsrc = KV[w];      // wave w owns q rows q0+64w..+63
  bf16x8 bQ[4][2];
#pragma unroll
  for (int qq = 0; qq < 4; ++qq) {
    const int qrow = qq * 16 + l16;
#pragma unroll
    for (int hh = 0; hh < 2; ++hh)
      bQ[qq][hh] = *(const bf16x8*)(Qsrc + qrow * 64 + (((hh * 4 + quad) ^ sel) << 3));
  }
  __syncthreads();   // all waves done reading Q before K0/V0 overwrite

  async16(Kp + (size_t)(ks0 + srow) * 64 + sc, KV[0] + tid * 8);
  async16(Kp + (size_t)(ks0 + 32 + srow) * 64 + sc, KV[0] + 2048 + tid * 8);
  async16(Vp + (size_t)srow * SEQ + ks0 + sc, KV[2] + tid * 8);
  async16(Vp + (size_t)(32 + srow) * SEQ + ks0 + sc, KV[2] + 2048 + tid * 8);

  union { unsigned short u[8]; bf16x8 v; } one8;
#pragma unroll
  for (int t = 0; t < 8; ++t) one8.u[t] = 0x3F80;
  const bf16x8 aOnes = one8.v;

  f32x4 o_acc[4][4];
  f32x4 l_acc[4];
  const f32x4 zinit = {-12.f, -12.f, -12.f, -12.f};  // fixed softmax max
#pragma unroll
  for (int qq = 0; qq < 4; ++qq) {
    f32x4 z = {0.f, 0.f, 0.f, 0.f};
    l_acc[qq] = z;
#pragma unroll
    for (int dt = 0; dt < 4; ++dt) o_acc[qq][dt] = z;
  }

  for (int it = 0; it < 16; ++it) {
    const int cur = it & 1;
    __syncthreads();
    if (it + 1 < 16) {
      const int kt = ks0 + (it + 1) * 64, nb = (it + 1) & 1;
      async16(Kp + (size_t)(kt + srow) * 64 + sc, KV[nb] + tid * 8);
      async16(Kp + (size_t)(kt + 32 + srow) * 64 + sc, KV[nb] + 2048 + tid * 8);
      async16(Vp + (size_t)srow * SEQ + kt + sc, KV[2 + nb] + tid * 8);
      async16(Vp + (size_t)(32 + srow) * SEQ + kt + sc, KV[2 + nb] + 2048 + tid * 8);
    }
    const unsigned short* Ks = KV[cur];
    const unsigned short* Vs = KV[2 + cur];

    // S^T - 12 and P = exp2(.), packed per-qq to limit register liveness
    bf16x8 bP[4][2];
#pragma unroll
    for (int kk = 0; kk < 4; ++kk) {
      const int krow = kk * 16 + l16;
      bf16x8 a0 = *(const bf16x8*)(Ks + krow * 64 + ((quad ^ sel) << 3));
      bf16x8 a1 = *(const bf16x8*)(Ks + krow * 64 + (((4 + quad) ^ sel) << 3));
#pragma unroll
      for (int qq = 0; qq < 4; ++qq) {
        f32x4 z = __builtin_amdgcn_mfma_f32_16x16x32_bf16(a0, bQ[qq][0], zinit, 0, 0, 0);
        z = __builtin_amdgcn_mfma_f32_16x16x32_bf16(a1, bQ[qq][1], z, 0, 0, 0);
#pragma unroll
        for (int r = 0; r < 4; ++r) z[r] = __builtin_amdgcn_exp2f(z[r]);
        unsigned lo = pkbf(z[0], z[1]);
        unsigned hi = pkbf(z[2], z[3]);
        union { unsigned d[4]; bf16x8 v; } pk;
        pk.v = bP[qq][kk >> 1];
        pk.d[(kk & 1) * 2] = lo;
        pk.d[(kk & 1) * 2 + 1] = hi;
        bP[qq][kk >> 1] = pk.v;
      }
    }

    // denominator via ones-MFMA (all C rows identical = per-q sum)
#pragma unroll
    for (int qq = 0; qq < 4; ++qq)
#pragma unroll
      for (int G = 0; G < 2; ++G)
        l_acc[qq] = __builtin_amdgcn_mfma_f32_16x16x32_bf16(aOnes, bP[qq][G], l_acc[qq], 0, 0, 0);

    // O^T += Vt * P, permuted k-slot labeling; V frags shared across qq
#pragma unroll
    for (int dt = 0; dt < 4; ++dt) {
      const unsigned short* vbase = Vs + (dt * 16 + l16) * 64;
      const int inner = (quad & 1) * 4;
#pragma unroll
      for (int G = 0; G < 2; ++G) {
        const int c0 = 4 * G + (quad >> 1);
        bf16x4 lo = *(const bf16x4*)(vbase + ((c0 ^ sel) << 3) + inner);
        bf16x4 hi = *(const bf16x4*)(vbase + (((c0 + 2) ^ sel) << 3) + inner);
        bf16x8 aV = __builtin_shufflevector(lo, hi, 0, 1, 2, 3, 4, 5, 6, 7);
#pragma unroll
        for (int qq = 0; qq < 4; ++qq)
          o_acc[qq][dt] = __builtin_amdgcn_mfma_f32_16x16x32_bf16(aV, bP[qq][G], o_acc[qq][dt], 0, 0, 0);
      }
    }
  }

  // write partials: Op[ksl][bh][d][q] (bf16, unnormalized), Lp[ksl][bh][q]
  const size_t sb = (size_t)(ksl * 32 + bh);
#pragma unroll
  for (int qq = 0; qq < 4; ++qq) {
    const int qg = q0 + w * 64 + qq * 16 + l16;
#pragma unroll
    for (int dt = 0; dt < 4; ++dt)
#pragma unroll
      for (int r = 0; r < 4; ++r) {
        const int d = dt * 16 + quad * 4 + r;
        Op[(sb * 64 + d) * SEQ + qg] = f2bf(o_acc[qq][dt][r]);
      }
    if (quad == 0) Lp[sb * SEQ + qg] = l_acc[qq][0];
  }
}

// combine 2 key-slice partials + Gram-Schmidt exclusion -> O bf16 [token][ch]
__global__ __launch_bounds__(128) void combine_kernel(
    const unsigned short* __restrict__ Op, const float* __restrict__ Lp,
    const unsigned short* __restrict__ Vt, unsigned short* __restrict__ O) {
  const int bh = blockIdx.y;
  const int q = blockIdx.x * 128 + threadIdx.x;
  const size_t QC = (size_t)32 * SEQ;
  const size_t idx = (size_t)bh * SEQ + q;
  const float inv = 1.0f / (Lp[idx] + Lp[QC + idx]);
  const unsigned short* O1 = Op + (size_t)bh * 64 * SEQ + q;
  const unsigned short* O2 = O1 + QC * 64;
  const unsigned short* Vp = Vt + (size_t)bh * 64 * SEQ + q;
  float o64[64];
  float ov = 0.f, vv = 0.f;
#pragma unroll
  for (int d = 0; d < 64; ++d) {
    const float o = (bf2f(O1[(size_t)d * SEQ]) + bf2f(O2[(size_t)d * SEQ])) * inv;
    const float v = bf2f(Vp[(size_t)d * SEQ]);
    o64[d] = o; ov += o * v; vv += v * v;
  }
  const float align = ov / (vv + 1e-8f);
  const int b = bh >> 4, h = bh & 15;
  unsigned short* dst = O + (size_t)(b * SEQ + q) * DM + h * 64;
#pragma unroll
  for (int d = 0; d < 64; d += 2) {
    const float a0 = o64[d]     - align * bf2f(Vp[(size_t)d * SEQ]);
    const float a1 = o64[d + 1] - align * bf2f(Vp[(size_t)(d + 1) * SEQ]);
    *(unsigned*)(dst + d) = pkbf(a0, a1);
  }
}

// out = O @ Wo^T + bo, fp32 output. 64x128 tiles, BK=32 single-barrier dbuf.
__global__ __launch_bounds__(256) void out_gemm(
    const unsigned short* __restrict__ Ob, const unsigned short* __restrict__ wob,
    const float* __restrict__ bo, float* __restrict__ out) {
  __shared__ unsigned short As[2][64 * 32], Bs[2][128 * 32];   // 24 KB
  const int m0 = blockIdx.y * 64, n0 = blockIdx.x * 128;
  const int tid = threadIdx.x, lane = tid & 63, w = tid >> 6;
  const int wm = (w >> 1) * 32, wn = (w & 1) * 64;
  const int quad = lane >> 4, l16 = lane & 15;
  const int srow = tid >> 2;
  const int sc = (((tid & 3) ^ (srow & 3)) << 3);
  f32x4 acc[2][4];
#pragma unroll
  for (int i = 0; i < 2; ++i)
#pragma unroll
    for (int j = 0; j < 4; ++j) { f32x4 z = {0.f, 0.f, 0.f, 0.f}; acc[i][j] = z; }

  async16(Ob + (size_t)(m0 + srow) * 1024 + sc, As[0] + tid * 8);
  async16(wob + (size_t)(n0 + srow) * 1024 + sc, Bs[0] + tid * 8);
  async16(wob + (size_t)(n0 + 64 + srow) * 1024 + sc, Bs[0] + 2048 + tid * 8);

  for (int it = 0; it < 32; ++it) {
    const int cur = it & 1;
    __syncthreads();
    if (it + 1 < 32) {
      const int kt = (it + 1) * 32, nb = (it + 1) & 1;
      async16(Ob + (size_t)(m0 + srow) * 1024 + kt + sc, As[nb] + tid * 8);
      async16(wob + (size_t)(n0 + srow) * 1024 + kt + sc, Bs[nb] + tid * 8);
      async16(wob + (size_t)(n0 + 64 + srow) * 1024 + kt + sc, Bs[nb] + 2048 + tid * 8);
    }
    bf16x8 af[2], bf[4];
#pragma unroll
    for (int i = 0; i < 2; ++i) {
      const int r = wm + i * 16 + l16;
      af[i] = *(const bf16x8*)(As[cur] + r * 32 + ((quad ^ (r & 3)) << 3));
    }
#pragma unroll
    for (int j = 0; j < 4; ++j) {
      const int r = wn + j * 16 + l16;
      bf[j] = *(const bf16x8*)(Bs[cur] + r * 32 + ((quad ^ (r & 3)) << 3));
    }
#pragma unroll
    for (int i = 0; i < 2; ++i)
#pragma unroll
      for (int j = 0; j < 4; ++j)
        acc[i][j] = __builtin_amdgcn_mfma_f32_16x16x32_bf16(af[i], bf[j], acc[i][j], 0, 0, 0);
  }

#pragma unroll
  for (int i = 0; i < 2; ++i)
#pragma unroll
    for (int j = 0; j < 4; ++j) {
      const int col = n0 + wn + j * 16 + l16;
      const float bb = bo[col];
#pragma unroll
      for (int r = 0; r < 4; ++r) {
        const int m = m0 + wm + i * 16 + quad * 4 + r;
        out[(size_t)m * DM + col] = acc[i][j][r] + bb;
      }
    }
}

extern "C" void kernel_launch(void* const* d_in, const int* in_sizes, int n_in,
                              void* d_out, int out_size, void* d_ws, size_t ws_size,
                              hipStream_t stream) {
  const float* x  = (const float*)d_in[0];
  const float* wq = (const float*)d_in[1];
  const float* bq = (const float*)d_in[2];
  const float* wk = (const float*)d_in[3];
  const float* bk = (const float*)d_in[4];
  const float* wv = (const float*)d_in[5];
  const float* bv = (const float*)d_in[6];
  const float* wo = (const float*)d_in[7];
  const float* bo = (const float*)d_in[8];
  float* out = (float*)d_out;
  (void)in_sizes; (void)n_in; (void)out_size; (void)ws_size;

  unsigned short* ws  = (unsigned short*)d_ws;
  unsigned short* xb  = ws;                         // 4096*1024
  unsigned short* wqb = xb + (size_t)NTOK * DM;     // 1024*1024 each (contiguous!)
  unsigned short* wkb = wqb + (size_t)DM * DM;
  unsigned short* wvb = wkb + (size_t)DM * DM;
  unsigned short* wob = wvb + (size_t)DM * DM;
  unsigned short* Qb  = wob + (size_t)DM * DM;      // [32][2048][64]
  unsigned short* Kb  = Qb + (size_t)NTOK * DM;
  unsigned short* Vtb = Kb + (size_t)NTOK * DM;     // [32][64][2048]
  unsigned short* Ob  = Vtb + (size_t)NTOK * DM;    // [4096][1024]
  unsigned short* Opb = Ob + (size_t)NTOK * DM;     // [2][32][64][2048] bf16
  float* Lpw = (float*)(Opb + (size_t)2 * 32 * 64 * SEQ);  // [2][32][2048]

  cast_all<<<8192, 256, 0, stream>>>(x, wq, wk, wv, wo, ws);
  qkv_gemm<<<768, 256, 0, stream>>>(xb, wqb, wkb, wvb, bq, bk, bv, Qb, Kb, Vtb);
  attn_kernel<<<512, 256, 0, stream>>>(Qb, Kb, Vtb, Opb, Lpw);
  combine_kernel<<<dim3(16, 32), 128, 0, stream>>>(Opb, Lpw, Vtb, Ob);
  out_gemm<<<dim3(8, 64), 256, 0, stream>>>(Ob, wob, bo, out);
}

// Round 10
// 194.310 us; speedup vs baseline: 1.0825x; 1.0825x over previous
//
#include <hip/hip_runtime.h>
#include <stdint.h>

#define SEQ 2048
#define NTOK 4096          // B*S
#define DM 1024

typedef __bf16 bf16x8 __attribute__((ext_vector_type(8)));
typedef __bf16 bf16x4 __attribute__((ext_vector_type(4)));
typedef float f32x4 __attribute__((ext_vector_type(4)));

__device__ __forceinline__ unsigned short f2bf(float f) {
  union { float f; unsigned u; } v; v.f = f;
  return (unsigned short)((v.u + 0x7fffu + ((v.u >> 16) & 1u)) >> 16);
}
__device__ __forceinline__ float bf2f(unsigned short s) {
  union { unsigned u; float f; } v; v.u = ((unsigned)s) << 16; return v.f;
}
// pack two floats to packed bf16 (round-half-up) in ONE v_perm + 2 adds
__device__ __forceinline__ unsigned pkbf(float a, float b) {
  union { float f; unsigned u; } x, y; x.f = a; y.f = b;
  return __builtin_amdgcn_perm(y.u + 0x8000u, x.u + 0x8000u, 0x07060302u);
}

// async global->LDS, 16B per lane. LDS dest must be wave-uniform base + lane*16.
__device__ __forceinline__ void async16(const unsigned short* g, unsigned short* l) {
  __builtin_amdgcn_global_load_lds(
      (const __attribute__((address_space(1))) void*)g,
      (__attribute__((address_space(3))) void*)l, 16, 0, 0);
}

// one kernel casts x + all 4 weights (contiguous in ws)
__global__ __launch_bounds__(256) void cast_all(
    const float* __restrict__ x, const float* __restrict__ wq,
    const float* __restrict__ wk, const float* __restrict__ wv,
    const float* __restrict__ wo, unsigned short* __restrict__ dst) {
  size_t i = ((size_t)blockIdx.x * 256 + threadIdx.x) * 4;
  const float* src; size_t off;
  if (i < (size_t)NTOK * DM) { src = x; off = i; }
  else {
    size_t j = i - (size_t)NTOK * DM;
    int s = (int)(j >> 20);
    src = (s == 0) ? wq : (s == 1) ? wk : (s == 2) ? wv : wo;
    off = j & 1048575u;
  }
  float4 f = *(const float4*)(src + off);
  ushort4 o;
  o.x = f2bf(f.x); o.y = f2bf(f.y); o.z = f2bf(f.z); o.w = f2bf(f.w);
  *(ushort4*)(dst + i) = o;
}

// ---- 128x128 GEMM core, BK=64, XOR-swizzled LDS (16B chunk c of row r at
// chunk c^(r&7)): proven ZERO bank conflicts (R8). Two-barrier K-loop.
__device__ __forceinline__ void gemm128_bk64(
    const unsigned short* __restrict__ A, const unsigned short* __restrict__ Bw,
    int m0, int n0, f32x4 acc[4][4], unsigned short* As, unsigned short* Bs) {
  const int tid = threadIdx.x, lane = tid & 63, w = tid >> 6;
  const int wm = (w >> 1) * 64, wn = (w & 1) * 64;
  const int quad = lane >> 4, l16 = lane & 15, sel = l16 & 7;
  const int srow = tid >> 3;                       // 0..31
  const int sc = ((tid & 7) ^ (srow & 7)) << 3;    // swizzled chunk offset

  for (int kt = 0; kt < 1024; kt += 64) {
    __syncthreads();
#pragma unroll
    for (int c = 0; c < 4; ++c) {
      const int row = c * 32 + srow;
      async16(A + (size_t)(m0 + row) * 1024 + kt + sc, As + c * 2048 + tid * 8);
      async16(Bw + (size_t)(n0 + row) * 1024 + kt + sc, Bs + c * 2048 + tid * 8);
    }
    __syncthreads();
#pragma unroll
    for (int ks = 0; ks < 2; ++ks) {
      bf16x8 af[4], bf[4];
#pragma unroll
      for (int i = 0; i < 4; ++i)
        af[i] = *(const bf16x8*)(As + (wm + i * 16 + l16) * 64 + (((ks * 4 + quad) ^ sel) << 3));
#pragma unroll
      for (int j = 0; j < 4; ++j)
        bf[j] = *(const bf16x8*)(Bs + (wn + j * 16 + l16) * 64 + (((ks * 4 + quad) ^ sel) << 3));
#pragma unroll
      for (int i = 0; i < 4; ++i)
#pragma unroll
        for (int j = 0; j < 4; ++j)
          acc[i][j] = __builtin_amdgcn_mfma_f32_16x16x32_bf16(af[i], bf[j], acc[i][j], 0, 0, 0);
    }
  }
}

// QKV projection. R8 inner structure + R9 XCD-grouped decode: each XCD owns a
// 512-token slab of x (1 MB, L2-resident) for all 3 kinds.
// kind 0=Q (scaled log2e/8), 1=K, 2=V^T (A/B swapped for coalesced store).
__global__ __launch_bounds__(256) void qkv_gemm(
    const unsigned short* __restrict__ xb,
    const unsigned short* __restrict__ wqb, const unsigned short* __restrict__ wkb,
    const unsigned short* __restrict__ wvb,
    const float* __restrict__ bq, const float* __restrict__ bk, const float* __restrict__ bv,
    unsigned short* __restrict__ Q, unsigned short* __restrict__ Kd,
    unsigned short* __restrict__ Vt) {
  __shared__ unsigned short As[128 * 64], Bs[128 * 64];   // 32 KB
  const int gx = blockIdx.x;
  const int kind = gx >> 8;
  const int rr = gx & 255;
  const int tok = 4 * (rr & 7) + ((rr >> 3) & 3);   // 0..31, XCD-grouped slabs
  const int oth = rr >> 5;                           // 0..7
  const unsigned short* A; const unsigned short* Bw;
  int m0, n0;
  if (kind == 2) { A = wvb; Bw = xb; m0 = oth * 128; n0 = tok * 128; }
  else { A = xb; Bw = kind ? wkb : wqb; m0 = tok * 128; n0 = oth * 128; }

  f32x4 acc[4][4];
#pragma unroll
  for (int i = 0; i < 4; ++i)
#pragma unroll
    for (int j = 0; j < 4; ++j) { f32x4 z = {0.f, 0.f, 0.f, 0.f}; acc[i][j] = z; }
  gemm128_bk64(A, Bw, m0, n0, acc, As, Bs);

  const int lane = threadIdx.x & 63, w = threadIdx.x >> 6;
  const int quad = lane >> 4, l16 = lane & 15;
  const int wm = (w >> 1) * 64, wn = (w & 1) * 64;

  if (kind == 2) {
    // m = channel, n = token
#pragma unroll
    for (int i = 0; i < 4; ++i)
#pragma unroll
      for (int j = 0; j < 4; ++j) {
        const int n = n0 + wn + j * 16 + l16;
        const int tb = n >> 11, s = n & 2047;
#pragma unroll
        for (int r = 0; r < 4; ++r) {
          const int m = m0 + wm + i * 16 + quad * 4 + r;
          const int h = m >> 6, d = m & 63;
          Vt[((size_t)(tb * 16 + h) * 64 + d) * SEQ + s] = f2bf(acc[i][j][r] + bv[m]);
        }
      }
  } else {
    const float* bias = (kind == 0) ? bq : bk;
    const float scale = (kind == 0) ? 0.180336880f : 1.0f;  // log2(e)/8 for Q
#pragma unroll
    for (int i = 0; i < 4; ++i)
#pragma unroll
      for (int j = 0; j < 4; ++j) {
        const int col = n0 + wn + j * 16 + l16;
        const float bb = bias[col];
        const int h = col >> 6, d = col & 63;
#pragma unroll
        for (int r = 0; r < 4; ++r) {
          const int m = m0 + wm + i * 16 + quad * 4 + r;
          const int b = m >> 11, s = m & 2047;
          const int bh = b * 16 + h;
          const unsigned short val = f2bf((acc[i][j][r] + bb) * scale);
          if (kind == 0) Q[((size_t)bh * SEQ + s) * 64 + d] = val;
          else           Kd[((size_t)bh * SEQ + s) * 64 + d] = val;
        }
      }
  }
}

// Flash attention, split-K (2 key slices of 1024), S^T form, log2-domain,
// FIXED-MAX softmax P = exp2(s-12) (the -12 rides in the MFMA C-init).
// q-tile 256/block, 4 qq groups/wave; Q staged via all 4 KV buffers then
// consumed to registers; K/V double-buffer, 1 barrier/iter. XCD-aware grid.
__global__ __launch_bounds__(256, 2) void attn_kernel(
    const unsigned short* __restrict__ Q, const unsigned short* __restrict__ Kd,
    const unsigned short* __restrict__ Vt,
    unsigned short* __restrict__ Op, float* __restrict__ Lp) {
  __shared__ unsigned short KV[4][4096];   // 32KB total
  const int gx = blockIdx.x;
  const int xcd = gx & 7;
  const int idx = gx >> 3;                 // 0..63
  const int bh  = xcd * 4 + (idx & 3);
  const int ksl = (idx >> 2) & 1;
  const int q0  = (idx >> 3) * 256;        // 0..7 -> q-tile base
  const int ks0 = ksl << 10;               // key slice base
  const int tid = threadIdx.x, lane = tid & 63, w = tid >> 6;
  const int quad = lane >> 4, l16 = lane & 15;
  const unsigned short* Qp = Q + (size_t)bh * SEQ * 64;
  const unsigned short* Kp = Kd + (size_t)bh * SEQ * 64;
  const unsigned short* Vp = Vt + (size_t)bh * 64 * SEQ;
  const int srow = tid >> 3;
  const int sc = ((tid & 7) ^ (srow & 7)) << 3;   // XOR-swizzled chunk

  // stage Q rows q0..q0+255 into KV[0..3] (64 rows per buffer)
#pragma unroll
  for (int c = 0; c < 8; ++c)
    async16(Qp + (size_t)(q0 + c * 32 + srow) * 64 + sc,
            KV[c >> 1] + (c & 1) * 2048 + tid * 8);
  __syncthreads();

  const int sel = l16 & 7;
  const unsigned short* Qsrc = KV[w];      // wave w owns q rows q0+64w..+63
  bf16x8 bQ[4][2];
#pragma unroll
  for (int qq = 0; qq < 4; ++qq) {
    const int qrow = qq * 16 + l16;
#pragma unroll
    for (int hh = 0; hh < 2; ++hh)
      bQ[qq][hh] = *(const bf16x8*)(Qsrc + qrow * 64 + (((hh * 4 + quad) ^ sel) << 3));
  }
  __syncthreads();   // all waves done reading Q before K0/V0 overwrite

  async16(Kp + (size_t)(ks0 + srow) * 64 + sc, KV[0] + tid * 8);
  async16(Kp + (size_t)(ks0 + 32 + srow) * 64 + sc, KV[0] + 2048 + tid * 8);
  async16(Vp + (size_t)srow * SEQ + ks0 + sc, KV[2] + tid * 8);
  async16(Vp + (size_t)(32 + srow) * SEQ + ks0 + sc, KV[2] + 2048 + tid * 8);

  union { unsigned short u[8]; bf16x8 v; } one8;
#pragma unroll
  for (int t = 0; t < 8; ++t) one8.u[t] = 0x3F80;
  const bf16x8 aOnes = one8.v;

  f32x4 o_acc[4][4];
  f32x4 l_acc[4];
  const f32x4 zinit = {-12.f, -12.f, -12.f, -12.f};  // fixed softmax max
#pragma unroll
  for (int qq = 0; qq < 4; ++qq) {
    f32x4 z = {0.f, 0.f, 0.f, 0.f};
    l_acc[qq] = z;
#pragma unroll
    for (int dt = 0; dt < 4; ++dt) o_acc[qq][dt] = z;
  }

  for (int it = 0; it < 16; ++it) {
    const int cur = it & 1;
    __syncthreads();
    if (it + 1 < 16) {
      const int kt = ks0 + (it + 1) * 64, nb = (it + 1) & 1;
      async16(Kp + (size_t)(kt + srow) * 64 + sc, KV[nb] + tid * 8);
      async16(Kp + (size_t)(kt + 32 + srow) * 64 + sc, KV[nb] + 2048 + tid * 8);
      async16(Vp + (size_t)srow * SEQ + kt + sc, KV[2 + nb] + tid * 8);
      async16(Vp + (size_t)(32 + srow) * SEQ + kt + sc, KV[2 + nb] + 2048 + tid * 8);
    }
    const unsigned short* Ks = KV[cur];
    const unsigned short* Vs = KV[2 + cur];

    // S^T - 12 and P = exp2(.), packed per-qq to limit register liveness
    bf16x8 bP[4][2];
#pragma unroll
    for (int kk = 0; kk < 4; ++kk) {
      const int krow = kk * 16 + l16;
      bf16x8 a0 = *(const bf16x8*)(Ks + krow * 64 + ((quad ^ sel) << 3));
      bf16x8 a1 = *(const bf16x8*)(Ks + krow * 64 + (((4 + quad) ^ sel) << 3));
#pragma unroll
      for (int qq = 0; qq < 4; ++qq) {
        f32x4 z = __builtin_amdgcn_mfma_f32_16x16x32_bf16(a0, bQ[qq][0], zinit, 0, 0, 0);
        z = __builtin_amdgcn_mfma_f32_16x16x32_bf16(a1, bQ[qq][1], z, 0, 0, 0);
#pragma unroll
        for (int r = 0; r < 4; ++r) z[r] = __builtin_amdgcn_exp2f(z[r]);
        unsigned lo = pkbf(z[0], z[1]);
        unsigned hi = pkbf(z[2], z[3]);
        union { unsigned d[4]; bf16x8 v; } pk;
        pk.v = bP[qq][kk >> 1];
        pk.d[(kk & 1) * 2] = lo;
        pk.d[(kk & 1) * 2 + 1] = hi;
        bP[qq][kk >> 1] = pk.v;
      }
    }

    // denominator via ones-MFMA (all C rows identical = per-q sum)
#pragma unroll
    for (int qq = 0; qq < 4; ++qq)
#pragma unroll
      for (int G = 0; G < 2; ++G)
        l_acc[qq] = __builtin_amdgcn_mfma_f32_16x16x32_bf16(aOnes, bP[qq][G], l_acc[qq], 0, 0, 0);

    // O^T += Vt * P, permuted k-slot labeling; V frags shared across qq
#pragma unroll
    for (int dt = 0; dt < 4; ++dt) {
      const unsigned short* vbase = Vs + (dt * 16 + l16) * 64;
      const int inner = (quad & 1) * 4;
#pragma unroll
      for (int G = 0; G < 2; ++G) {
        const int c0 = 4 * G + (quad >> 1);
        bf16x4 lo = *(const bf16x4*)(vbase + ((c0 ^ sel) << 3) + inner);
        bf16x4 hi = *(const bf16x4*)(vbase + (((c0 + 2) ^ sel) << 3) + inner);
        bf16x8 aV = __builtin_shufflevector(lo, hi, 0, 1, 2, 3, 4, 5, 6, 7);
#pragma unroll
        for (int qq = 0; qq < 4; ++qq)
          o_acc[qq][dt] = __builtin_amdgcn_mfma_f32_16x16x32_bf16(aV, bP[qq][G], o_acc[qq][dt], 0, 0, 0);
      }
    }
  }

  // write partials: Op[ksl][bh][d][q] (bf16, unnormalized), Lp[ksl][bh][q]
  const size_t sb = (size_t)(ksl * 32 + bh);
#pragma unroll
  for (int qq = 0; qq < 4; ++qq) {
    const int qg = q0 + w * 64 + qq * 16 + l16;
#pragma unroll
    for (int dt = 0; dt < 4; ++dt)
#pragma unroll
      for (int r = 0; r < 4; ++r) {
        const int d = dt * 16 + quad * 4 + r;
        Op[(sb * 64 + d) * SEQ + qg] = f2bf(o_acc[qq][dt][r]);
      }
    if (quad == 0) Lp[sb * SEQ + qg] = l_acc[qq][0];
  }
}

// combine 2 key-slice partials + Gram-Schmidt exclusion -> O bf16 [token][ch]
__global__ __launch_bounds__(128) void combine_kernel(
    const unsigned short* __restrict__ Op, const float* __restrict__ Lp,
    const unsigned short* __restrict__ Vt, unsigned short* __restrict__ O) {
  const int bh = blockIdx.y;
  const int q = blockIdx.x * 128 + threadIdx.x;
  const size_t QC = (size_t)32 * SEQ;
  const size_t idx = (size_t)bh * SEQ + q;
  const float inv = 1.0f / (Lp[idx] + Lp[QC + idx]);
  const unsigned short* O1 = Op + (size_t)bh * 64 * SEQ + q;
  const unsigned short* O2 = O1 + QC * 64;
  const unsigned short* Vp = Vt + (size_t)bh * 64 * SEQ + q;
  float o64[64];
  float ov = 0.f, vv = 0.f;
#pragma unroll
  for (int d = 0; d < 64; ++d) {
    const float o = (bf2f(O1[(size_t)d * SEQ]) + bf2f(O2[(size_t)d * SEQ])) * inv;
    const float v = bf2f(Vp[(size_t)d * SEQ]);
    o64[d] = o; ov += o * v; vv += v * v;
  }
  const float align = ov / (vv + 1e-8f);
  const int b = bh >> 4, h = bh & 15;
  unsigned short* dst = O + (size_t)(b * SEQ + q) * DM + h * 64;
#pragma unroll
  for (int d = 0; d < 64; d += 2) {
    const float a0 = o64[d]     - align * bf2f(Vp[(size_t)d * SEQ]);
    const float a1 = o64[d + 1] - align * bf2f(Vp[(size_t)(d + 1) * SEQ]);
    *(unsigned*)(dst + d) = pkbf(a0, a1);
  }
}

// out = O @ Wo^T + bo, fp32 output. 64x128 tiles, BK=64 swizzled (R8 version).
__global__ __launch_bounds__(256) void out_gemm(
    const unsigned short* __restrict__ Ob, const unsigned short* __restrict__ wob,
    const float* __restrict__ bo, float* __restrict__ out) {
  __shared__ unsigned short As[64 * 64], Bs[128 * 64];   // 24 KB
  const int m0 = blockIdx.y * 64, n0 = blockIdx.x * 128;
  const int tid = threadIdx.x, lane = tid & 63, w = tid >> 6;
  const int wm = (w >> 1) * 32, wn = (w & 1) * 64;
  const int quad = lane >> 4, l16 = lane & 15, sel = l16 & 7;
  const int srow = tid >> 3;
  const int sc = ((tid & 7) ^ (srow & 7)) << 3;
  f32x4 acc[2][4];
#pragma unroll
  for (int i = 0; i < 2; ++i)
#pragma unroll
    for (int j = 0; j < 4; ++j) { f32x4 z = {0.f, 0.f, 0.f, 0.f}; acc[i][j] = z; }

  for (int kt = 0; kt < 1024; kt += 64) {
    __syncthreads();
#pragma unroll
    for (int c = 0; c < 2; ++c) {
      const int row = c * 32 + srow;
      async16(Ob + (size_t)(m0 + row) * 1024 + kt + sc, As + c * 2048 + tid * 8);
    }
#pragma unroll
    for (int c = 0; c < 4; ++c) {
      const int row = c * 32 + srow;
      async16(wob + (size_t)(n0 + row) * 1024 + kt + sc, Bs + c * 2048 + tid * 8);
    }
    __syncthreads();
#pragma unroll
    for (int ks = 0; ks < 2; ++ks) {
      bf16x8 af[2], bf[4];
#pragma unroll
      for (int i = 0; i < 2; ++i)
        af[i] = *(const bf16x8*)(As + (wm + i * 16 + l16) * 64 + (((ks * 4 + quad) ^ sel) << 3));
#pragma unroll
      for (int j = 0; j < 4; ++j)
        bf[j] = *(const bf16x8*)(Bs + (wn + j * 16 + l16) * 64 + (((ks * 4 + quad) ^ sel) << 3));
#pragma unroll
      for (int i = 0; i < 2; ++i)
#pragma unroll
        for (int j = 0; j < 4; ++j)
          acc[i][j] = __builtin_amdgcn_mfma_f32_16x16x32_bf16(af[i], bf[j], acc[i][j], 0, 0, 0);
    }
  }

#pragma unroll
  for (int i = 0; i < 2; ++i)
#pragma unroll
    for (int j = 0; j < 4; ++j) {
      const int col = n0 + wn + j * 16 + l16;
      const float bb = bo[col];
#pragma unroll
      for (int r = 0; r < 4; ++r) {
        const int m = m0 + wm + i * 16 + quad * 4 + r;
        out[(size_t)m * DM + col] = acc[i][j][r] + bb;
      }
    }
}

extern "C" void kernel_launch(void* const* d_in, const int* in_sizes, int n_in,
                              void* d_out, int out_size, void* d_ws, size_t ws_size,
                              hipStream_t stream) {
  const float* x  = (const float*)d_in[0];
  const float* wq = (const float*)d_in[1];
  const float* bq = (const float*)d_in[2];
  const float* wk = (const float*)d_in[3];
  const float* bk = (const float*)d_in[4];
  const float* wv = (const float*)d_in[5];
  const float* bv = (const float*)d_in[6];
  const float* wo = (const float*)d_in[7];
  const float* bo = (const float*)d_in[8];
  float* out = (float*)d_out;
  (void)in_sizes; (void)n_in; (void)out_size; (void)ws_size;

  unsigned short* ws  = (unsigned short*)d_ws;
  unsigned short* xb  = ws;                         // 4096*1024
  unsigned short* wqb = xb + (size_t)NTOK * DM;     // 1024*1024 each (contiguous!)
  unsigned short* wkb = wqb + (size_t)DM * DM;
  unsigned short* wvb = wkb + (size_t)DM * DM;
  unsigned short* wob = wvb + (size_t)DM * DM;
  unsigned short* Qb  = wob + (size_t)DM * DM;      // [32][2048][64]
  unsigned short* Kb  = Qb + (size_t)NTOK * DM;
  unsigned short* Vtb = Kb + (size_t)NTOK * DM;     // [32][64][2048]
  unsigned short* Ob  = Vtb + (size_t)NTOK * DM;    // [4096][1024]
  unsigned short* Opb = Ob + (size_t)NTOK * DM;     // [2][32][64][2048] bf16
  float* Lpw = (float*)(Opb + (size_t)2 * 32 * 64 * SEQ);  // [2][32][2048]

  cast_all<<<8192, 256, 0, stream>>>(x, wq, wk, wv, wo, ws);
  qkv_gemm<<<768, 256, 0, stream>>>(xb, wqb, wkb, wvb, bq, bk, bv, Qb, Kb, Vtb);
  attn_kernel<<<512, 256, 0, stream>>>(Qb, Kb, Vtb, Opb, Lpw);
  combine_kernel<<<dim3(16, 32), 128, 0, stream>>>(Opb, Lpw, Vtb, Ob);
  out_gemm<<<dim3(8, 64), 256, 0, stream>>>(Ob, wob, bo, out);
}